// Round 16
// baseline (372.846 us; speedup 1.0000x reference)
//
#include <hip/hip_runtime.h>
#include <hip/hip_bf16.h>

#define T_TOK 4096
#define D_DIM 2048
#define E_EXP 8
#define HE    1376
#define O_DIM 2048
#define TPB   8      // tokens per gating block
#define WN4   5636096  // 22544384/4 float4s per expert-weight array

typedef __attribute__((ext_vector_type(8))) short bf16x8;
typedef __attribute__((ext_vector_type(4))) float f32x4;

static __device__ __forceinline__ short f2bf(float f) {
  unsigned u = __builtin_bit_cast(unsigned, f);
  unsigned r = (u + 0x7fffu + ((u >> 16) & 1u)) >> 16;
  return (short)(r & 0xffffu);
}

static __device__ __forceinline__ unsigned long long pack4bf(float a, float b, float c, float d) {
  return (unsigned long long)(unsigned short)f2bf(a)
       | ((unsigned long long)(unsigned short)f2bf(b) << 16)
       | ((unsigned long long)(unsigned short)f2bf(c) << 32)
       | ((unsigned long long)(unsigned short)f2bf(d) << 48);
}

// async global->LDS, 16B per lane; LDS dest is wave-uniform base + lane*16
static __device__ __forceinline__ void gld16(const void* g, void* l) {
  __builtin_amdgcn_global_load_lds(
      (const __attribute__((address_space(1))) unsigned*)g,
      (__attribute__((address_space(3))) unsigned*)l, 16, 0, 0);
}

// ---------------- fp32 -> bf16 segment converter ----------------
static __device__ __forceinline__ void cvt_body(const float* __restrict__ src, short* __restrict__ dst,
                                                int b, int nblk) {
  int i = b * 256 + (int)threadIdx.x;
  int stride = nblk * 256;
  for (; i < WN4; i += stride) {
    float4 v = ((const float4*)src)[i];
    ((unsigned long long*)dst)[i] = pack4bf(v.x, v.y, v.z, v.w);
  }
}

__global__ __launch_bounds__(256) void cvt_seg(const float* __restrict__ src, short* __restrict__ dst) {
  cvt_body(src, dst, blockIdx.x, gridDim.x);
}

// ---------------- fused prep: gating (blocks 0..511) + weight conversions ---------------
__global__ __launch_bounds__(256) void prep_mega(
    const float* __restrict__ x, const float* __restrict__ noise,
    const float* __restrict__ wg1, const float* __restrict__ wg2,
    const float* __restrict__ wn,
    const float* __restrict__ wg, const float* __restrict__ wu, const float* __restrict__ wd,
    short* __restrict__ wgb, short* __restrict__ wub, short* __restrict__ wdb,
    float* __restrict__ imp, float* __restrict__ loadv,
    int* __restrict__ counts, int* __restrict__ tokslot, float* __restrict__ scorelist,
    short* __restrict__ xbf) {
  int bid = blockIdx.x;
  if (bid >= 512) {
    int c = bid - 512;
    if (c < 2048)      cvt_body(wg, wgb, c, 2048);
    else if (c < 4096) cvt_body(wu, wub, c - 2048, 2048);
    else               cvt_body(wd, wdb, c - 4096, 2048);
    return;
  }
  __shared__ float red[TPB][17];
  __shared__ float s_wg2[64];
  __shared__ float blk_imp[8], blk_load[8];
  __shared__ int cnt[8], base[8];

  int tid = threadIdx.x, lane = tid & 63, w = tid >> 6;
  int t0 = bid * TPB;
  if (tid < 64) s_wg2[tid] = wg2[tid];
  if (tid < 8) { blk_imp[tid] = 0.f; blk_load[tid] = 0.f; cnt[tid] = 0; }
  __syncthreads();

  {
    int tb = t0 + w * 2;
    float acc[2][16];
#pragma unroll
    for (int a = 0; a < 2; ++a)
#pragma unroll
      for (int o = 0; o < 16; ++o) acc[a][o] = 0.f;
    for (int j = 0; j < 8; ++j) {
      int col = j * 64 + lane;
      float4 xv[2];
#pragma unroll
      for (int a = 0; a < 2; ++a) {
        xv[a] = ((const float4*)(x + (size_t)(tb + a) * D_DIM))[col];
        ((unsigned long long*)(xbf + (size_t)(tb + a) * D_DIM))[col] =
            pack4bf(xv[a].x, xv[a].y, xv[a].z, xv[a].w);
      }
#pragma unroll
      for (int o = 0; o < 16; ++o) {
        const float* wrow = (o < 8) ? (wg1 + (size_t)o * D_DIM) : (wn + (size_t)(o - 8) * D_DIM);
        float4 wv = ((const float4*)wrow)[col];
#pragma unroll
        for (int a = 0; a < 2; ++a)
          acc[a][o] += xv[a].x * wv.x + xv[a].y * wv.y + xv[a].z * wv.z + xv[a].w * wv.w;
      }
    }
#pragma unroll
    for (int a = 0; a < 2; ++a)
#pragma unroll
      for (int o = 0; o < 16; ++o) {
        float v = acc[a][o];
        v += __shfl_xor(v, 1);  v += __shfl_xor(v, 2);  v += __shfl_xor(v, 4);
        v += __shfl_xor(v, 8);  v += __shfl_xor(v, 16); v += __shfl_xor(v, 32);
        if (lane == 0) red[w * 2 + a][o] = v;
      }
  }
  __syncthreads();

  int i0 = 0, i1 = 0, r0 = 0, r1 = 0;
  float s0 = 0.f, s1 = 0.f;
  if (tid < TPB) {
    int t = t0 + tid;
    float lg[8], nc[8], lt[8], ag[8];
#pragma unroll
    for (int f = 0; f < 8; ++f) ag[f] = tanhf(red[tid][f]);
#pragma unroll
    for (int e = 0; e < 8; ++e) {
      float s = 0.f;
#pragma unroll
      for (int f = 0; f < 8; ++f) s += ag[f] * s_wg2[e * 8 + f];
      lg[e] = s;
      float xr = red[tid][8 + e];
      float sp = fmaxf(xr, 0.f) + log1pf(expf(-fabsf(xr)));
      nc[e] = sp + 0.01f;
      lt[e] = lg[e] + nc[e] * noise[(size_t)t * 8 + e];
    }
    float v0 = -INFINITY, v1 = -INFINITY, v2 = -INFINITY;
#pragma unroll
    for (int e = 0; e < 8; ++e) {
      float v = lt[e];
      if (v > v0)      { v2 = v1; v1 = v0; i1 = i0; v0 = v; i0 = e; }
      else if (v > v1) { v2 = v1; v1 = v; i1 = e; }
      else if (v > v2) { v2 = v; }
    }
    float e1 = expf(v1 - v0);
    s0 = 1.f / (1.f + e1);
    s1 = e1 * s0;
    atomicAdd(&blk_imp[i0], s0);
    atomicAdd(&blk_imp[i1], s1);
    r0 = atomicAdd(&cnt[i0], 1);
    r1 = atomicAdd(&cnt[i1], 1);
#pragma unroll
    for (int e = 0; e < 8; ++e) {
      float thr = (lt[e] > v2) ? v2 : v1;
      float z = (lg[e] - thr) / nc[e];
      atomicAdd(&blk_load[e], 0.5f * (1.f + erff(z * 0.70710678118654752f)));
    }
  }
  __syncthreads();
  if (tid < 8) {
    base[tid] = atomicAdd(&counts[tid], cnt[tid]);
    atomicAdd(&imp[tid], blk_imp[tid]);
    atomicAdd(&loadv[tid], blk_load[tid]);
  }
  __syncthreads();
  if (tid < TPB) {
    int t = t0 + tid;
    int p0 = base[i0] + r0;
    tokslot[i0 * T_TOK + p0] = t * 2 + 0;
    scorelist[i0 * T_TOK + p0] = s0;
    int p1 = base[i1] + r1;
    tokslot[i1 * T_TOK + p1] = t * 2 + 1;
    scorelist[i1 * T_TOK + p1] = s1;
  }
}

// ---------------- gate loss ----------------
__global__ void loss_kernel(const float* __restrict__ imp, const float* __restrict__ loadv,
                            float* __restrict__ out_loss) {
  if (threadIdx.x == 0 && blockIdx.x == 0) {
    float mi = 0.f, ml = 0.f;
    for (int e = 0; e < 8; ++e) { mi += imp[e]; ml += loadv[e]; }
    mi *= 0.125f; ml *= 0.125f;
    float vi = 0.f, vl = 0.f;
    for (int e = 0; e < 8; ++e) {
      float a = imp[e] - mi, b = loadv[e] - ml;
      vi += a * a; vl += b * b;
    }
    vi /= 7.f; vl /= 7.f;
    *out_loss = 0.01f * (vi / (mi * mi + 1e-10f) + vl / (ml * ml + 1e-10f));
  }
}

// ---------------- combine (2 planes): y[t] = part[2t] + part[2t+1] ----------------
__global__ __launch_bounds__(256) void combine_y(const float* __restrict__ part, float* __restrict__ y) {
  int i = blockIdx.x * 256 + threadIdx.x;
  int stride = gridDim.x * 256;
  const int C4 = O_DIM / 4;
  for (; i < (T_TOK * O_DIM) / 4; i += stride) {
    int t = i / C4;
    int c = i - t * C4;
    float4 a = ((const float4*)part)[(size_t)(2 * t) * C4 + c];
    float4 b = ((const float4*)part)[(size_t)(2 * t + 1) * C4 + c];
    float4 r;
    r.x = a.x + b.x; r.y = a.y + b.y; r.z = a.z + b.z; r.w = a.w + b.w;
    ((float4*)y)[i] = r;
  }
}

// ---------------- combine (4 planes: 2 slots x 2 K-halves) ----------------
__global__ __launch_bounds__(256) void combine_y4(const float* __restrict__ part, float* __restrict__ y) {
  int i = blockIdx.x * 256 + threadIdx.x;
  int stride = gridDim.x * 256;
  const int C4 = O_DIM / 4;
  const size_t KS = (size_t)2 * T_TOK * C4;   // float4s per K-half plane-set
  for (; i < (T_TOK * O_DIM) / 4; i += stride) {
    int t = i / C4;
    int c = i - t * C4;
    size_t b0 = (size_t)(2 * t) * C4 + c;
    size_t b1 = (size_t)(2 * t + 1) * C4 + c;
    float4 a = ((const float4*)part)[b0];
    float4 b = ((const float4*)part)[b1];
    float4 cc = ((const float4*)part)[KS + b0];
    float4 d = ((const float4*)part)[KS + b1];
    float4 r;
    r.x = a.x + b.x + cc.x + d.x;
    r.y = a.y + b.y + cc.y + d.y;
    r.z = a.z + b.z + cc.z + d.z;
    r.w = a.w + b.w + cc.w + d.w;
    ((float4*)y)[i] = r;
  }
}

// ================= FAST PATH gu (r14-verbatim: de-aliased decode) =======================
__global__ __launch_bounds__(256) void gemm_gu_fast(
    const short* __restrict__ xbf, const short* __restrict__ wgb, const short* __restrict__ wub,
    const float* __restrict__ bg, const float* __restrict__ bu,
    const int* __restrict__ counts, const int* __restrict__ tokslot,
    short* __restrict__ H) {
  int bid = blockIdx.x;          // grid = 5632
  int e = bid & 7;
  int rem = bid >> 3;            // 0..703
  int mt = rem / 22;             // 0..31 (not ≡ rem mod 32 -> no CU starvation)
  int nt = rem % 22;             // 0..21
  int R = counts[e];
  int m0 = mt * 128;
  if (m0 >= R) return;
  int n0 = nt * 64;

  __shared__ short As[128 * 32];
  __shared__ short Bgs[64 * 32];
  __shared__ short Bus[64 * 32];
  __shared__ int rows_tok[128];

  int tid = threadIdx.x;
  if (tid < 128) {
    int pos = m0 + tid;
    rows_tok[tid] = (pos < R) ? tokslot[e * T_TOK + pos] : -1;
  }
  __syncthreads();

  int w = tid >> 6, li = tid & 63;
  int rp = li >> 2;
  int slotg = (li & 3) ^ ((rp >> 1) & 3);
  int ra0 = 16 * w + rp, ra1 = 64 + 16 * w + rp;
  int ts0 = rows_tok[ra0], ts1 = rows_tok[ra1];
  const short* pA0 = xbf + (size_t)(ts0 < 0 ? 0 : (ts0 >> 1)) * D_DIM + slotg * 8;
  const short* pA1 = xbf + (size_t)(ts1 < 0 ? 0 : (ts1 >> 1)) * D_DIM + slotg * 8;
  int nb = n0 + 16 * w + rp; if (nb > HE - 1) nb = HE - 1;
  const short* pBg = wgb + ((size_t)e * HE + nb) * D_DIM + slotg * 8;
  const short* pBu = wub + ((size_t)e * HE + nb) * D_DIM + slotg * 8;
  short* dA0 = &As[(16 * w) * 32];
  short* dA1 = &As[(64 + 16 * w) * 32];
  short* dBg = &Bgs[(16 * w) * 32];
  short* dBu = &Bus[(16 * w) * 32];

  int lane = tid & 63, wid = tid >> 6;
  int wm = wid >> 1, wnn = wid & 1;
  int lr = lane & 15, kg = lane >> 4;
  int ko = (kg ^ ((lr >> 1) & 3)) * 8;
  const short* aptr[4];
  const short* gptr[2];
  const short* uptr[2];
#pragma unroll
  for (int mi = 0; mi < 4; ++mi) aptr[mi] = &As[(wm * 64 + mi * 16 + lr) * 32 + ko];
#pragma unroll
  for (int ni = 0; ni < 2; ++ni) {
    gptr[ni] = &Bgs[(wnn * 32 + ni * 16 + lr) * 32 + ko];
    uptr[ni] = &Bus[(wnn * 32 + ni * 16 + lr) * 32 + ko];
  }

  f32x4 accg[4][2], accu[4][2];
#pragma unroll
  for (int mi = 0; mi < 4; ++mi)
#pragma unroll
    for (int ni = 0; ni < 2; ++ni) {
      accg[mi][ni] = (f32x4){0.f, 0.f, 0.f, 0.f};
      accu[mi][ni] = (f32x4){0.f, 0.f, 0.f, 0.f};
    }

  for (int k0 = 0; k0 < D_DIM; k0 += 32) {
    gld16(pA0, dA0); pA0 += 32;
    gld16(pA1, dA1); pA1 += 32;
    gld16(pBg, dBg); pBg += 32;
    gld16(pBu, dBu); pBu += 32;
    __syncthreads();
    bf16x8 af[4], gf[2], uf[2];
#pragma unroll
    for (int mi = 0; mi < 4; ++mi) af[mi] = *(const bf16x8*)aptr[mi];
#pragma unroll
    for (int ni = 0; ni < 2; ++ni) {
      gf[ni] = *(const bf16x8*)gptr[ni];
      uf[ni] = *(const bf16x8*)uptr[ni];
    }
#pragma unroll
    for (int mi = 0; mi < 4; ++mi)
#pragma unroll
      for (int ni = 0; ni < 2; ++ni) {
        accg[mi][ni] = __builtin_amdgcn_mfma_f32_16x16x32_bf16(af[mi], gf[ni], accg[mi][ni], 0, 0, 0);
        accu[mi][ni] = __builtin_amdgcn_mfma_f32_16x16x32_bf16(af[mi], uf[ni], accu[mi][ni], 0, 0, 0);
      }
    __syncthreads();
  }

#pragma unroll
  for (int ni = 0; ni < 2; ++ni) {
    int n = n0 + wnn * 32 + ni * 16 + lr;
    if (n >= HE) continue;
    float bgv = bg[e * HE + n];
    float buv = bu[e * HE + n];
#pragma unroll
    for (int mi = 0; mi < 4; ++mi) {
#pragma unroll
      for (int j = 0; j < 4; ++j) {
        int row = wm * 64 + mi * 16 + (lane >> 4) * 4 + j;
        int ts = rows_tok[row];
        if (ts < 0) continue;
        float g = accg[mi][ni][j] + bgv;
        float u = accu[mi][ni][j] + buv;
        float h = (g / (1.f + expf(-g))) * u;
        H[(size_t)ts * HE + n] = f2bf(h);
      }
    }
  }
}

// down body: PS=0 atomic into y; PS=1 plain store into per-slot plane (with K-range)
template <int PS>
static __device__ __forceinline__ void down_core(
    const short* __restrict__ H, const short* __restrict__ wdb, const float* __restrict__ bd,
    const int* __restrict__ counts, const int* __restrict__ tokslot,
    const float* __restrict__ scorelist, float* __restrict__ out,
    int e, int mt, int nt, int kbeg, int kend, int addBias) {
  int R = counts[e];
  int m0 = mt * 128;
  if (m0 >= R) return;
  int n0 = nt * 128;

  __shared__ short As[128 * 32];
  __shared__ short Bs[128 * 32];
  __shared__ int rows_tok[128];
  __shared__ float rows_sc[128];

  int tid = threadIdx.x;
  if (tid < 128) {
    int pos = m0 + tid;
    if (pos < R) {
      rows_tok[tid] = tokslot[e * T_TOK + pos];
      rows_sc[tid] = scorelist[e * T_TOK + pos];
    } else {
      rows_tok[tid] = -1;
      rows_sc[tid] = 0.f;
    }
  }
  __syncthreads();

  int w = tid >> 6, li = tid & 63;
  int rp = li >> 2;
  int slotg = (li & 3) ^ ((rp >> 1) & 3);
  int ra0 = 16 * w + rp, ra1 = 64 + 16 * w + rp;
  int ts0 = rows_tok[ra0], ts1 = rows_tok[ra1];
  const short* pA0 = H + (size_t)(ts0 < 0 ? 0 : ts0) * HE + kbeg + slotg * 8;
  const short* pA1 = H + (size_t)(ts1 < 0 ? 0 : ts1) * HE + kbeg + slotg * 8;
  const short* pB0 = wdb + ((size_t)e * O_DIM + n0 + 16 * w + rp) * HE + kbeg + slotg * 8;
  const short* pB1 = wdb + ((size_t)e * O_DIM + n0 + 64 + 16 * w + rp) * HE + kbeg + slotg * 8;
  short* dA0 = &As[(16 * w) * 32];
  short* dA1 = &As[(64 + 16 * w) * 32];
  short* dB0 = &Bs[(16 * w) * 32];
  short* dB1 = &Bs[(64 + 16 * w) * 32];

  int lane = tid & 63, wid = tid >> 6;
  int wm = wid >> 1, wnn = wid & 1;
  int lr = lane & 15, kg = lane >> 4;
  int ko = (kg ^ ((lr >> 1) & 3)) * 8;
  const short* aptr[4];
  const short* bptr[4];
#pragma unroll
  for (int mi = 0; mi < 4; ++mi) aptr[mi] = &As[(wm * 64 + mi * 16 + lr) * 32 + ko];
#pragma unroll
  for (int ni = 0; ni < 4; ++ni) bptr[ni] = &Bs[(wnn * 64 + ni * 16 + lr) * 32 + ko];

  f32x4 acc[4][4];
#pragma unroll
  for (int mi = 0; mi < 4; ++mi)
#pragma unroll
    for (int ni = 0; ni < 4; ++ni) acc[mi][ni] = (f32x4){0.f, 0.f, 0.f, 0.f};

  for (int k0 = kbeg; k0 < kend; k0 += 32) {
    gld16(pA0, dA0); pA0 += 32;
    gld16(pA1, dA1); pA1 += 32;
    gld16(pB0, dB0); pB0 += 32;
    gld16(pB1, dB1); pB1 += 32;
    __syncthreads();
    bf16x8 af[4], bf[4];
#pragma unroll
    for (int mi = 0; mi < 4; ++mi) af[mi] = *(const bf16x8*)aptr[mi];
#pragma unroll
    for (int ni = 0; ni < 4; ++ni) bf[ni] = *(const bf16x8*)bptr[ni];
#pragma unroll
    for (int mi = 0; mi < 4; ++mi)
#pragma unroll
      for (int ni = 0; ni < 4; ++ni)
        acc[mi][ni] = __builtin_amdgcn_mfma_f32_16x16x32_bf16(af[mi], bf[ni], acc[mi][ni], 0, 0, 0);
    __syncthreads();
  }

#pragma unroll
  for (int ni = 0; ni < 4; ++ni) {
    int n = n0 + wnn * 64 + ni * 16 + lr;
    float bdv = addBias ? bd[e * O_DIM + n] : 0.f;
#pragma unroll
    for (int mi = 0; mi < 4; ++mi) {
#pragma unroll
      for (int j = 0; j < 4; ++j) {
        int row = wm * 64 + mi * 16 + (lane >> 4) * 4 + j;
        int ts = rows_tok[row];
        if (ts < 0) continue;
        float sc = rows_sc[row];
        float v = sc * (acc[mi][ni][j] + bdv);
        if (PS) {
          out[(size_t)ts * O_DIM + n] = v;
        } else {
          int t = ts >> 1;
          atomicAdd(&out[(size_t)t * O_DIM + n], v);
        }
      }
    }
  }
}

__global__ __launch_bounds__(256) void gemm_down_fast(
    const short* __restrict__ H, const short* __restrict__ wdb, const float* __restrict__ bd,
    const int* __restrict__ counts, const int* __restrict__ tokslot,
    const float* __restrict__ scorelist, float* __restrict__ y) {
  int bid = blockIdx.x;          // grid = 4096
  int e = bid & 7;
  int rem = bid >> 3;
  down_core<0>(H, wdb, bd, counts, tokslot, scorelist, y,
               e, rem >> 4, rem & 15, 0, HE, 1);
}

__global__ __launch_bounds__(256) void gemm_down_ps(
    const short* __restrict__ H, const short* __restrict__ wdb, const float* __restrict__ bd,
    const int* __restrict__ counts, const int* __restrict__ tokslot,
    const float* __restrict__ scorelist, float* __restrict__ part) {
  int bid = blockIdx.x;          // grid = 4096
  int e = bid & 7;
  int rem = bid >> 3;
  down_core<1>(H, wdb, bd, counts, tokslot, scorelist, part,
               e, rem >> 4, rem & 15, 0, HE, 1);
}

// K-split x2: plane ks at part + ks*8192*O_DIM; bias applied only at ks==0
__global__ __launch_bounds__(256) void gemm_down_ks(
    const short* __restrict__ H, const short* __restrict__ wdb, const float* __restrict__ bd,
    const int* __restrict__ counts, const int* __restrict__ tokslot,
    const float* __restrict__ scorelist, float* __restrict__ part) {
  int bid = blockIdx.x;          // grid = 8192
  int e = bid & 7;
  int rem = bid >> 3;            // 0..1023
  int mt = rem >> 5;             // 0..31 (spreads over CUs)
  int low = rem & 31;
  int nt = low >> 1;             // 0..15
  int ks = low & 1;              // K-half
  int kbeg = ks ? 704 : 0;       // 704 = 22*32; remainder 672 = 21*32
  int kend = ks ? HE : 704;
  float* out = part + (size_t)ks * 2 * T_TOK * O_DIM;
  down_core<1>(H, wdb, bd, counts, tokslot, scorelist, out,
               e, mt, nt, kbeg, kend, ks == 0 ? 1 : 0);
}

// ================= FALLBACK PATH (fp32 weights, reg convert) ============
__global__ __launch_bounds__(256) void gemm_gu_slow(
    const short* __restrict__ xbf, const float* __restrict__ wg, const float* __restrict__ wu,
    const float* __restrict__ bg, const float* __restrict__ bu,
    const int* __restrict__ counts, const int* __restrict__ tokslot,
    short* __restrict__ H) {
  const int NT = 22, MT = 32;
  int bid = blockIdx.x;
  int e = bid / (MT * NT);
  int rem = bid % (MT * NT);
  int mt = rem / NT, nt = rem % NT;
  int R = counts[e];
  int m0 = mt * 128;
  if (m0 >= R) return;
  int n0 = nt * 64;

  __shared__ short As[128 * 40];
  __shared__ short Bs[2][64 * 40];
  __shared__ int rows_tok[128];

  int tid = threadIdx.x;
  if (tid < 128) {
    int pos = m0 + tid;
    rows_tok[tid] = (pos < R) ? tokslot[e * T_TOK + pos] : -1;
  }
  __syncthreads();

  int rA = tid >> 2, cA = tid & 3;
  int tsA0 = rows_tok[rA];
  int tsA1 = rows_tok[rA + 64];
  const short* srcA0 = xbf + (size_t)(tsA0 < 0 ? 0 : (tsA0 >> 1)) * D_DIM + cA * 8;
  const short* srcA1 = xbf + (size_t)(tsA1 < 0 ? 0 : (tsA1 >> 1)) * D_DIM + cA * 8;
  short* dstA0 = As + rA * 40 + cA * 8;
  short* dstA1 = As + (rA + 64) * 40 + cA * 8;

  const float* srcB[4];
  short* dstB[4];
#pragma unroll
  for (int j = 0; j < 4; ++j) {
    int idx = tid + j * 256;
    int mat = idx >> 9;
    int p = idx & 511;
    int row = p >> 3, c4 = p & 7;
    int sr = n0 + row;
    if (sr > HE - 1) sr = HE - 1;
    srcB[j] = (mat ? wu : wg) + ((size_t)e * HE + sr) * D_DIM + c4 * 4;
    dstB[j] = &Bs[mat][row * 40 + c4 * 4];
  }

  int lane = tid & 63, wid = tid >> 6;
  int wm = wid >> 1, wnn = wid & 1;
  int lr = lane & 15, lk = (lane >> 4) * 8;
  const short* aptr[4];
  const short* gptr[2];
  const short* uptr[2];
#pragma unroll
  for (int mi = 0; mi < 4; ++mi) aptr[mi] = As + (wm * 64 + mi * 16 + lr) * 40 + lk;
#pragma unroll
  for (int ni = 0; ni < 2; ++ni) {
    gptr[ni] = &Bs[0][(wnn * 32 + ni * 16 + lr) * 40 + lk];
    uptr[ni] = &Bs[1][(wnn * 32 + ni * 16 + lr) * 40 + lk];
  }

  f32x4 accg[4][2], accu[4][2];
#pragma unroll
  for (int mi = 0; mi < 4; ++mi)
#pragma unroll
    for (int ni = 0; ni < 2; ++ni) {
      accg[mi][ni] = (f32x4){0.f, 0.f, 0.f, 0.f};
      accu[mi][ni] = (f32x4){0.f, 0.f, 0.f, 0.f};
    }

  for (int k0 = 0; k0 < D_DIM; k0 += 32) {
    *(int4*)dstA0 = *(const int4*)(srcA0 + k0);
    *(int4*)dstA1 = *(const int4*)(srcA1 + k0);
#pragma unroll
    for (int j = 0; j < 4; ++j) {
      float4 v = *(const float4*)(srcB[j] + k0);
      *(unsigned long long*)dstB[j] = pack4bf(v.x, v.y, v.z, v.w);
    }
    __syncthreads();
    bf16x8 af[4], gf[2], uf[2];
#pragma unroll
    for (int mi = 0; mi < 4; ++mi) af[mi] = *(const bf16x8*)aptr[mi];
#pragma unroll
    for (int ni = 0; ni < 2; ++ni) {
      gf[ni] = *(const bf16x8*)gptr[ni];
      uf[ni] = *(const bf16x8*)uptr[ni];
    }
#pragma unroll
    for (int mi = 0; mi < 4; ++mi)
#pragma unroll
      for (int ni = 0; ni < 2; ++ni) {
        accg[mi][ni] = __builtin_amdgcn_mfma_f32_16x16x32_bf16(af[mi], gf[ni], accg[mi][ni], 0, 0, 0);
        accu[mi][ni] = __builtin_amdgcn_mfma_f32_16x16x32_bf16(af[mi], uf[ni], accu[mi][ni], 0, 0, 0);
      }
    __syncthreads();
  }

#pragma unroll
  for (int ni = 0; ni < 2; ++ni) {
    int n = n0 + wnn * 32 + ni * 16 + lr;
    if (n >= HE) continue;
    float bgv = bg[e * HE + n];
    float buv = bu[e * HE + n];
#pragma unroll
    for (int mi = 0; mi < 4; ++mi) {
#pragma unroll
      for (int j = 0; j < 4; ++j) {
        int row = wm * 64 + mi * 16 + (lane >> 4) * 4 + j;
        int ts = rows_tok[row];
        if (ts < 0) continue;
        float g = accg[mi][ni][j] + bgv;
        float u = accu[mi][ni][j] + buv;
        float h = (g / (1.f + expf(-g))) * u;
        H[(size_t)ts * HE + n] = f2bf(h);
      }
    }
  }
}

__global__ __launch_bounds__(256) void gemm_down_slow(
    const short* __restrict__ H, const float* __restrict__ wd, const float* __restrict__ bd,
    const int* __restrict__ counts, const int* __restrict__ tokslot,
    const float* __restrict__ scorelist, float* __restrict__ y) {
  const int NT = 32, MT = 32;
  int bid = blockIdx.x;
  int e = bid / (MT * NT);
  int rem = bid % (MT * NT);
  int mt = rem / NT, nt = rem % NT;
  int R = counts[e];
  int m0 = mt * 128;
  if (m0 >= R) return;
  int n0 = nt * 64;

  __shared__ short As[128 * 40];
  __shared__ short Bs[64 * 40];
  __shared__ int rows_tok[128];
  __shared__ float rows_sc[128];

  int tid = threadIdx.x;
  if (tid < 128) {
    int pos = m0 + tid;
    if (pos < R) {
      rows_tok[tid] = tokslot[e * T_TOK + pos];
      rows_sc[tid] = scorelist[e * T_TOK + pos];
    } else {
      rows_tok[tid] = -1;
      rows_sc[tid] = 0.f;
    }
  }
  __syncthreads();

  int rA = tid >> 2, cA = tid & 3;
  int tsA0 = rows_tok[rA];
  int tsA1 = rows_tok[rA + 64];
  const short* srcA0 = H + (size_t)(tsA0 < 0 ? 0 : tsA0) * HE + cA * 8;
  const short* srcA1 = H + (size_t)(tsA1 < 0 ? 0 : tsA1) * HE + cA * 8;
  short* dstA0 = As + rA * 40 + cA * 8;
  short* dstA1 = As + (rA + 64) * 40 + cA * 8;

  int rB = tid >> 3, cB = tid & 7;
  const float* srcB0 = wd + ((size_t)e * O_DIM + n0 + rB) * HE + cB * 4;
  const float* srcB1 = wd + ((size_t)e * O_DIM + n0 + rB + 32) * HE + cB * 4;
  short* dstB0 = Bs + rB * 40 + cB * 4;
  short* dstB1 = Bs + (rB + 32) * 40 + cB * 4;

  int lane = tid & 63, wid = tid >> 6;
  int wm = wid >> 1, wnn = wid & 1;
  int lr = lane & 15, lk = (lane >> 4) * 8;
  const short* aptr[4];
  const short* bptr[2];
#pragma unroll
  for (int mi = 0; mi < 4; ++mi) aptr[mi] = As + (wm * 64 + mi * 16 + lr) * 40 + lk;
#pragma unroll
  for (int ni = 0; ni < 2; ++ni) bptr[ni] = Bs + (wnn * 32 + ni * 16 + lr) * 40 + lk;

  f32x4 acc[4][2];
#pragma unroll
  for (int mi = 0; mi < 4; ++mi)
#pragma unroll
    for (int ni = 0; ni < 2; ++ni) acc[mi][ni] = (f32x4){0.f, 0.f, 0.f, 0.f};

  for (int k0 = 0; k0 < HE; k0 += 32) {
    *(int4*)dstA0 = *(const int4*)(srcA0 + k0);
    *(int4*)dstA1 = *(const int4*)(srcA1 + k0);
    {
      float4 v0 = *(const float4*)(srcB0 + k0);
      float4 v1 = *(const float4*)(srcB1 + k0);
      *(unsigned long long*)dstB0 = pack4bf(v0.x, v0.y, v0.z, v0.w);
      *(unsigned long long*)dstB1 = pack4bf(v1.x, v1.y, v1.z, v1.w);
    }
    __syncthreads();
    bf16x8 af[4], bf[2];
#pragma unroll
    for (int mi = 0; mi < 4; ++mi) af[mi] = *(const bf16x8*)aptr[mi];
#pragma unroll
    for (int ni = 0; ni < 2; ++ni) bf[ni] = *(const bf16x8*)bptr[ni];
#pragma unroll
    for (int mi = 0; mi < 4; ++mi)
#pragma unroll
      for (int ni = 0; ni < 2; ++ni)
        acc[mi][ni] = __builtin_amdgcn_mfma_f32_16x16x32_bf16(af[mi], bf[ni], acc[mi][ni], 0, 0, 0);
    __syncthreads();
  }

#pragma unroll
  for (int ni = 0; ni < 2; ++ni) {
    int n = n0 + wnn * 32 + ni * 16 + lr;
    float bdv = bd[e * O_DIM + n];
#pragma unroll
    for (int mi = 0; mi < 4; ++mi) {
#pragma unroll
      for (int j = 0; j < 4; ++j) {
        int row = wm * 64 + mi * 16 + (lane >> 4) * 4 + j;
        int ts = rows_tok[row];
        if (ts < 0) continue;
        float sc = rows_sc[row];
        int t = ts >> 1;
        atomicAdd(&y[(size_t)t * O_DIM + n], sc * (acc[mi][ni][j] + bdv));
      }
    }
  }
}

extern "C" void kernel_launch(void* const* d_in, const int* in_sizes, int n_in,
                              void* d_out, int out_size, void* d_ws, size_t ws_size,
                              hipStream_t stream) {
  const float* x     = (const float*)d_in[0];
  const float* noise = (const float*)d_in[1];
  const float* wg1   = (const float*)d_in[2];
  const float* wg2   = (const float*)d_in[3];
  const float* wn    = (const float*)d_in[4];
  const float* wg    = (const float*)d_in[5];
  const float* wu    = (const float*)d_in[6];
  const float* wd    = (const float*)d_in[7];
  const float* bg    = (const float*)d_in[8];
  const float* bu    = (const float*)d_in[9];
  const float* bd    = (const float*)d_in[10];
  float* y = (float*)d_out;

  // layout: ctl | tokslot@256 | scorelst@131328 | xbf@262400 | H@17039616
  //   wgb@39584000 | wub@84672768 -> 129761536 (TIER1)
  //   wdb2@129761536 -> 174850304 (TIER2)
  //   part@174850304 (67108864) -> 241959168 (TIER3)
  //   part plane 2 @241959168 (67108864) -> 309068032 (TIER4, K-split down)
  char* ws = (char*)d_ws;
  float* imp      = (float*)(ws + 0);
  float* loadv    = (float*)(ws + 32);
  int*   counts   = (int*)(ws + 64);
  int*   tokslot  = (int*)(ws + 256);
  float* scorelst = (float*)(ws + 131328);
  short* xbf      = (short*)(ws + 262400);
  short* Hbuf     = (short*)(ws + 17039616);
  short* wgb      = (short*)(ws + 39584000);
  short* wub      = (short*)(ws + 84672768);
  short* wdb1     = (short*)(ws + 39584000);    // tier1: reuse wgb after gemm_gu
  short* wdb2     = (short*)(ws + 129761536);   // tier2+: independent
  float* part     = (float*)(ws + 174850304);   // tier3/4: per-slot partials
  const size_t TIER1 = 129761536;
  const size_t TIER2 = 174850304;
  const size_t TIER3 = 241959168;
  const size_t TIER4 = 309068032;

  hipMemsetAsync(d_ws, 0, 96, stream);

  if (ws_size >= TIER4) {
    prep_mega<<<6656, 256, 0, stream>>>(x, noise, wg1, wg2, wn, wg, wu, wd, wgb, wub, wdb2,
                                        imp, loadv, counts, tokslot, scorelst, xbf);
    loss_kernel<<<1, 64, 0, stream>>>(imp, loadv, y + (size_t)T_TOK * O_DIM);
    gemm_gu_fast<<<5632, 256, 0, stream>>>(xbf, wgb, wub, bg, bu, counts, tokslot, Hbuf);
    gemm_down_ks<<<8192, 256, 0, stream>>>(Hbuf, wdb2, bd, counts, tokslot, scorelst, part);
    combine_y4<<<2048, 256, 0, stream>>>(part, y);
  } else if (ws_size >= TIER3) {
    prep_mega<<<6656, 256, 0, stream>>>(x, noise, wg1, wg2, wn, wg, wu, wd, wgb, wub, wdb2,
                                        imp, loadv, counts, tokslot, scorelst, xbf);
    loss_kernel<<<1, 64, 0, stream>>>(imp, loadv, y + (size_t)T_TOK * O_DIM);
    gemm_gu_fast<<<5632, 256, 0, stream>>>(xbf, wgb, wub, bg, bu, counts, tokslot, Hbuf);
    gemm_down_ps<<<4096, 256, 0, stream>>>(Hbuf, wdb2, bd, counts, tokslot, scorelst, part);
    combine_y<<<2048, 256, 0, stream>>>(part, y);
  } else if (ws_size >= TIER2) {
    hipMemsetAsync(d_out, 0, (size_t)T_TOK * O_DIM * sizeof(float), stream);
    prep_mega<<<6656, 256, 0, stream>>>(x, noise, wg1, wg2, wn, wg, wu, wd, wgb, wub, wdb2,
                                        imp, loadv, counts, tokslot, scorelst, xbf);
    loss_kernel<<<1, 64, 0, stream>>>(imp, loadv, y + (size_t)T_TOK * O_DIM);
    gemm_gu_fast<<<5632, 256, 0, stream>>>(xbf, wgb, wub, bg, bu, counts, tokslot, Hbuf);
    gemm_down_fast<<<4096, 256, 0, stream>>>(Hbuf, wdb2, bd, counts, tokslot, scorelst, y);
  } else if (ws_size >= TIER1) {
    hipMemsetAsync(d_out, 0, (size_t)T_TOK * O_DIM * sizeof(float), stream);
    prep_mega<<<4608, 256, 0, stream>>>(x, noise, wg1, wg2, wn, wg, wu, wd, wgb, wub, wdb2,
                                        imp, loadv, counts, tokslot, scorelst, xbf);
    loss_kernel<<<1, 64, 0, stream>>>(imp, loadv, y + (size_t)T_TOK * O_DIM);
    gemm_gu_fast<<<5632, 256, 0, stream>>>(xbf, wgb, wub, bg, bu, counts, tokslot, Hbuf);
    cvt_seg<<<2048, 256, 0, stream>>>(wd, wdb1);
    gemm_down_fast<<<4096, 256, 0, stream>>>(Hbuf, wdb1, bd, counts, tokslot, scorelst, y);
  } else {
    hipMemsetAsync(d_out, 0, (size_t)T_TOK * O_DIM * sizeof(float), stream);
    prep_mega<<<512, 256, 0, stream>>>(x, noise, wg1, wg2, wn, wg, wu, wd, wgb, wub, wdb2,
                                       imp, loadv, counts, tokslot, scorelst, xbf);
    loss_kernel<<<1, 64, 0, stream>>>(imp, loadv, y + (size_t)T_TOK * O_DIM);
    gemm_gu_slow<<<E_EXP * 32 * 22, 256, 0, stream>>>(xbf, wg, wu, bg, bu, counts, tokslot, Hbuf);
    gemm_down_slow<<<E_EXP * 32 * 32, 256, 0, stream>>>(Hbuf, wd, bd, counts, tokslot, scorelst, y);
  }
}

// Round 17
// 349.441 us; speedup vs baseline: 1.0670x; 1.0670x over previous
//
#include <hip/hip_runtime.h>
#include <hip/hip_bf16.h>

#define T_TOK 4096
#define D_DIM 2048
#define E_EXP 8
#define HE    1376
#define O_DIM 2048
#define TPB   8      // tokens per gating block
#define WN4   5636096  // 22544384/4 float4s per expert-weight array

typedef __attribute__((ext_vector_type(8))) short bf16x8;
typedef __attribute__((ext_vector_type(4))) float f32x4;

static __device__ __forceinline__ short f2bf(float f) {
  unsigned u = __builtin_bit_cast(unsigned, f);
  unsigned r = (u + 0x7fffu + ((u >> 16) & 1u)) >> 16;
  return (short)(r & 0xffffu);
}

static __device__ __forceinline__ unsigned long long pack4bf(float a, float b, float c, float d) {
  return (unsigned long long)(unsigned short)f2bf(a)
       | ((unsigned long long)(unsigned short)f2bf(b) << 16)
       | ((unsigned long long)(unsigned short)f2bf(c) << 32)
       | ((unsigned long long)(unsigned short)f2bf(d) << 48);
}

// async global->LDS, 16B per lane; LDS dest is wave-uniform base + lane*16
static __device__ __forceinline__ void gld16(const void* g, void* l) {
  __builtin_amdgcn_global_load_lds(
      (const __attribute__((address_space(1))) unsigned*)g,
      (__attribute__((address_space(3))) unsigned*)l, 16, 0, 0);
}

// ---------------- fp32 -> bf16 segment converter ----------------
static __device__ __forceinline__ void cvt_body(const float* __restrict__ src, short* __restrict__ dst,
                                                int b, int nblk) {
  int i = b * 256 + (int)threadIdx.x;
  int stride = nblk * 256;
  for (; i < WN4; i += stride) {
    float4 v = ((const float4*)src)[i];
    ((unsigned long long*)dst)[i] = pack4bf(v.x, v.y, v.z, v.w);
  }
}

__global__ __launch_bounds__(256) void cvt_seg(const float* __restrict__ src, short* __restrict__ dst) {
  cvt_body(src, dst, blockIdx.x, gridDim.x);
}

// ---------------- fused prep: gating (blocks 0..511) + weight conversions ---------------
__global__ __launch_bounds__(256) void prep_mega(
    const float* __restrict__ x, const float* __restrict__ noise,
    const float* __restrict__ wg1, const float* __restrict__ wg2,
    const float* __restrict__ wn,
    const float* __restrict__ wg, const float* __restrict__ wu, const float* __restrict__ wd,
    short* __restrict__ wgb, short* __restrict__ wub, short* __restrict__ wdb,
    float* __restrict__ imp, float* __restrict__ loadv,
    int* __restrict__ counts, int* __restrict__ tokslot, float* __restrict__ scorelist,
    short* __restrict__ xbf) {
  int bid = blockIdx.x;
  if (bid >= 512) {
    int c = bid - 512;
    if (c < 2048)      cvt_body(wg, wgb, c, 2048);
    else if (c < 4096) cvt_body(wu, wub, c - 2048, 2048);
    else               cvt_body(wd, wdb, c - 4096, 2048);
    return;
  }
  __shared__ float red[TPB][17];
  __shared__ float s_wg2[64];
  __shared__ float blk_imp[8], blk_load[8];
  __shared__ int cnt[8], base[8];

  int tid = threadIdx.x, lane = tid & 63, w = tid >> 6;
  int t0 = bid * TPB;
  if (tid < 64) s_wg2[tid] = wg2[tid];
  if (tid < 8) { blk_imp[tid] = 0.f; blk_load[tid] = 0.f; cnt[tid] = 0; }
  __syncthreads();

  {
    int tb = t0 + w * 2;
    float acc[2][16];
#pragma unroll
    for (int a = 0; a < 2; ++a)
#pragma unroll
      for (int o = 0; o < 16; ++o) acc[a][o] = 0.f;
    for (int j = 0; j < 8; ++j) {
      int col = j * 64 + lane;
      float4 xv[2];
#pragma unroll
      for (int a = 0; a < 2; ++a) {
        xv[a] = ((const float4*)(x + (size_t)(tb + a) * D_DIM))[col];
        ((unsigned long long*)(xbf + (size_t)(tb + a) * D_DIM))[col] =
            pack4bf(xv[a].x, xv[a].y, xv[a].z, xv[a].w);
      }
#pragma unroll
      for (int o = 0; o < 16; ++o) {
        const float* wrow = (o < 8) ? (wg1 + (size_t)o * D_DIM) : (wn + (size_t)(o - 8) * D_DIM);
        float4 wv = ((const float4*)wrow)[col];
#pragma unroll
        for (int a = 0; a < 2; ++a)
          acc[a][o] += xv[a].x * wv.x + xv[a].y * wv.y + xv[a].z * wv.z + xv[a].w * wv.w;
      }
    }
#pragma unroll
    for (int a = 0; a < 2; ++a)
#pragma unroll
      for (int o = 0; o < 16; ++o) {
        float v = acc[a][o];
        v += __shfl_xor(v, 1);  v += __shfl_xor(v, 2);  v += __shfl_xor(v, 4);
        v += __shfl_xor(v, 8);  v += __shfl_xor(v, 16); v += __shfl_xor(v, 32);
        if (lane == 0) red[w * 2 + a][o] = v;
      }
  }
  __syncthreads();

  int i0 = 0, i1 = 0, r0 = 0, r1 = 0;
  float s0 = 0.f, s1 = 0.f;
  if (tid < TPB) {
    int t = t0 + tid;
    float lg[8], nc[8], lt[8], ag[8];
#pragma unroll
    for (int f = 0; f < 8; ++f) ag[f] = tanhf(red[tid][f]);
#pragma unroll
    for (int e = 0; e < 8; ++e) {
      float s = 0.f;
#pragma unroll
      for (int f = 0; f < 8; ++f) s += ag[f] * s_wg2[e * 8 + f];
      lg[e] = s;
      float xr = red[tid][8 + e];
      float sp = fmaxf(xr, 0.f) + log1pf(expf(-fabsf(xr)));
      nc[e] = sp + 0.01f;
      lt[e] = lg[e] + nc[e] * noise[(size_t)t * 8 + e];
    }
    float v0 = -INFINITY, v1 = -INFINITY, v2 = -INFINITY;
#pragma unroll
    for (int e = 0; e < 8; ++e) {
      float v = lt[e];
      if (v > v0)      { v2 = v1; v1 = v0; i1 = i0; v0 = v; i0 = e; }
      else if (v > v1) { v2 = v1; v1 = v; i1 = e; }
      else if (v > v2) { v2 = v; }
    }
    float e1 = expf(v1 - v0);
    s0 = 1.f / (1.f + e1);
    s1 = e1 * s0;
    atomicAdd(&blk_imp[i0], s0);
    atomicAdd(&blk_imp[i1], s1);
    r0 = atomicAdd(&cnt[i0], 1);
    r1 = atomicAdd(&cnt[i1], 1);
#pragma unroll
    for (int e = 0; e < 8; ++e) {
      float thr = (lt[e] > v2) ? v2 : v1;
      float z = (lg[e] - thr) / nc[e];
      atomicAdd(&blk_load[e], 0.5f * (1.f + erff(z * 0.70710678118654752f)));
    }
  }
  __syncthreads();
  if (tid < 8) {
    base[tid] = atomicAdd(&counts[tid], cnt[tid]);
    atomicAdd(&imp[tid], blk_imp[tid]);
    atomicAdd(&loadv[tid], blk_load[tid]);
  }
  __syncthreads();
  if (tid < TPB) {
    int t = t0 + tid;
    int p0 = base[i0] + r0;
    tokslot[i0 * T_TOK + p0] = t * 2 + 0;
    scorelist[i0 * T_TOK + p0] = s0;
    int p1 = base[i1] + r1;
    tokslot[i1 * T_TOK + p1] = t * 2 + 1;
    scorelist[i1 * T_TOK + p1] = s1;
  }
}

// ---------------- gate loss ----------------
__global__ void loss_kernel(const float* __restrict__ imp, const float* __restrict__ loadv,
                            float* __restrict__ out_loss) {
  if (threadIdx.x == 0 && blockIdx.x == 0) {
    float mi = 0.f, ml = 0.f;
    for (int e = 0; e < 8; ++e) { mi += imp[e]; ml += loadv[e]; }
    mi *= 0.125f; ml *= 0.125f;
    float vi = 0.f, vl = 0.f;
    for (int e = 0; e < 8; ++e) {
      float a = imp[e] - mi, b = loadv[e] - ml;
      vi += a * a; vl += b * b;
    }
    vi /= 7.f; vl /= 7.f;
    *out_loss = 0.01f * (vi / (mi * mi + 1e-10f) + vl / (ml * ml + 1e-10f));
  }
}

// ---------------- combine (2 planes): y[t] = part[2t] + part[2t+1] ----------------
__global__ __launch_bounds__(256) void combine_y(const float* __restrict__ part, float* __restrict__ y) {
  int i = blockIdx.x * 256 + threadIdx.x;
  int stride = gridDim.x * 256;
  const int C4 = O_DIM / 4;
  for (; i < (T_TOK * O_DIM) / 4; i += stride) {
    int t = i / C4;
    int c = i - t * C4;
    float4 a = ((const float4*)part)[(size_t)(2 * t) * C4 + c];
    float4 b = ((const float4*)part)[(size_t)(2 * t + 1) * C4 + c];
    float4 r;
    r.x = a.x + b.x; r.y = a.y + b.y; r.z = a.z + b.z; r.w = a.w + b.w;
    ((float4*)y)[i] = r;
  }
}

// ================= FAST PATH gu (de-aliased decode: mt NOT ≡ rem mod 32) ================
__global__ __launch_bounds__(256) void gemm_gu_fast(
    const short* __restrict__ xbf, const short* __restrict__ wgb, const short* __restrict__ wub,
    const float* __restrict__ bg, const float* __restrict__ bu,
    const int* __restrict__ counts, const int* __restrict__ tokslot,
    short* __restrict__ H) {
  int bid = blockIdx.x;          // grid = 5632
  int e = bid & 7;
  int rem = bid >> 3;            // 0..703
  int mt = rem / 22;             // 0..31 (varies with rem/32 -> spreads over CUs)
  int nt = rem % 22;             // 0..21
  int R = counts[e];
  int m0 = mt * 128;
  if (m0 >= R) return;
  int n0 = nt * 64;

  __shared__ short As[128 * 32];
  __shared__ short Bgs[64 * 32];
  __shared__ short Bus[64 * 32];
  __shared__ int rows_tok[128];

  int tid = threadIdx.x;
  if (tid < 128) {
    int pos = m0 + tid;
    rows_tok[tid] = (pos < R) ? tokslot[e * T_TOK + pos] : -1;
  }
  __syncthreads();

  int w = tid >> 6, li = tid & 63;
  int rp = li >> 2;
  int slotg = (li & 3) ^ ((rp >> 1) & 3);
  int ra0 = 16 * w + rp, ra1 = 64 + 16 * w + rp;
  int ts0 = rows_tok[ra0], ts1 = rows_tok[ra1];
  const short* pA0 = xbf + (size_t)(ts0 < 0 ? 0 : (ts0 >> 1)) * D_DIM + slotg * 8;
  const short* pA1 = xbf + (size_t)(ts1 < 0 ? 0 : (ts1 >> 1)) * D_DIM + slotg * 8;
  int nb = n0 + 16 * w + rp; if (nb > HE - 1) nb = HE - 1;
  const short* pBg = wgb + ((size_t)e * HE + nb) * D_DIM + slotg * 8;
  const short* pBu = wub + ((size_t)e * HE + nb) * D_DIM + slotg * 8;
  short* dA0 = &As[(16 * w) * 32];
  short* dA1 = &As[(64 + 16 * w) * 32];
  short* dBg = &Bgs[(16 * w) * 32];
  short* dBu = &Bus[(16 * w) * 32];

  int lane = tid & 63, wid = tid >> 6;
  int wm = wid >> 1, wnn = wid & 1;
  int lr = lane & 15, kg = lane >> 4;
  int ko = (kg ^ ((lr >> 1) & 3)) * 8;
  const short* aptr[4];
  const short* gptr[2];
  const short* uptr[2];
#pragma unroll
  for (int mi = 0; mi < 4; ++mi) aptr[mi] = &As[(wm * 64 + mi * 16 + lr) * 32 + ko];
#pragma unroll
  for (int ni = 0; ni < 2; ++ni) {
    gptr[ni] = &Bgs[(wnn * 32 + ni * 16 + lr) * 32 + ko];
    uptr[ni] = &Bus[(wnn * 32 + ni * 16 + lr) * 32 + ko];
  }

  f32x4 accg[4][2], accu[4][2];
#pragma unroll
  for (int mi = 0; mi < 4; ++mi)
#pragma unroll
    for (int ni = 0; ni < 2; ++ni) {
      accg[mi][ni] = (f32x4){0.f, 0.f, 0.f, 0.f};
      accu[mi][ni] = (f32x4){0.f, 0.f, 0.f, 0.f};
    }

  for (int k0 = 0; k0 < D_DIM; k0 += 32) {
    gld16(pA0, dA0); pA0 += 32;
    gld16(pA1, dA1); pA1 += 32;
    gld16(pBg, dBg); pBg += 32;
    gld16(pBu, dBu); pBu += 32;
    __syncthreads();
    bf16x8 af[4], gf[2], uf[2];
#pragma unroll
    for (int mi = 0; mi < 4; ++mi) af[mi] = *(const bf16x8*)aptr[mi];
#pragma unroll
    for (int ni = 0; ni < 2; ++ni) {
      gf[ni] = *(const bf16x8*)gptr[ni];
      uf[ni] = *(const bf16x8*)uptr[ni];
    }
#pragma unroll
    for (int mi = 0; mi < 4; ++mi)
#pragma unroll
      for (int ni = 0; ni < 2; ++ni) {
        accg[mi][ni] = __builtin_amdgcn_mfma_f32_16x16x32_bf16(af[mi], gf[ni], accg[mi][ni], 0, 0, 0);
        accu[mi][ni] = __builtin_amdgcn_mfma_f32_16x16x32_bf16(af[mi], uf[ni], accu[mi][ni], 0, 0, 0);
      }
    __syncthreads();
  }

#pragma unroll
  for (int ni = 0; ni < 2; ++ni) {
    int n = n0 + wnn * 32 + ni * 16 + lr;
    if (n >= HE) continue;
    float bgv = bg[e * HE + n];
    float buv = bu[e * HE + n];
#pragma unroll
    for (int mi = 0; mi < 4; ++mi) {
#pragma unroll
      for (int j = 0; j < 4; ++j) {
        int row = wm * 64 + mi * 16 + (lane >> 4) * 4 + j;
        int ts = rows_tok[row];
        if (ts < 0) continue;
        float g = accg[mi][ni][j] + bgv;
        float u = accu[mi][ni][j] + buv;
        float h = (g / (1.f + expf(-g))) * u;
        H[(size_t)ts * HE + n] = f2bf(h);
      }
    }
  }
}

// down body: PS=0 atomic into y; PS=1 plain store into per-slot plane
template <int PS>
static __device__ __forceinline__ void down_core(
    const short* __restrict__ H, const short* __restrict__ wdb, const float* __restrict__ bd,
    const int* __restrict__ counts, const int* __restrict__ tokslot,
    const float* __restrict__ scorelist, float* __restrict__ out,
    int e, int mt, int nt) {
  int R = counts[e];
  int m0 = mt * 128;
  if (m0 >= R) return;
  int n0 = nt * 128;

  __shared__ short As[128 * 32];
  __shared__ short Bs[128 * 32];
  __shared__ int rows_tok[128];
  __shared__ float rows_sc[128];

  int tid = threadIdx.x;
  if (tid < 128) {
    int pos = m0 + tid;
    if (pos < R) {
      rows_tok[tid] = tokslot[e * T_TOK + pos];
      rows_sc[tid] = scorelist[e * T_TOK + pos];
    } else {
      rows_tok[tid] = -1;
      rows_sc[tid] = 0.f;
    }
  }
  __syncthreads();

  int w = tid >> 6, li = tid & 63;
  int rp = li >> 2;
  int slotg = (li & 3) ^ ((rp >> 1) & 3);
  int ra0 = 16 * w + rp, ra1 = 64 + 16 * w + rp;
  int ts0 = rows_tok[ra0], ts1 = rows_tok[ra1];
  const short* pA0 = H + (size_t)(ts0 < 0 ? 0 : ts0) * HE + slotg * 8;
  const short* pA1 = H + (size_t)(ts1 < 0 ? 0 : ts1) * HE + slotg * 8;
  const short* pB0 = wdb + ((size_t)e * O_DIM + n0 + 16 * w + rp) * HE + slotg * 8;
  const short* pB1 = wdb + ((size_t)e * O_DIM + n0 + 64 + 16 * w + rp) * HE + slotg * 8;
  short* dA0 = &As[(16 * w) * 32];
  short* dA1 = &As[(64 + 16 * w) * 32];
  short* dB0 = &Bs[(16 * w) * 32];
  short* dB1 = &Bs[(64 + 16 * w) * 32];

  int lane = tid & 63, wid = tid >> 6;
  int wm = wid >> 1, wnn = wid & 1;
  int lr = lane & 15, kg = lane >> 4;
  int ko = (kg ^ ((lr >> 1) & 3)) * 8;
  const short* aptr[4];
  const short* bptr[4];
#pragma unroll
  for (int mi = 0; mi < 4; ++mi) aptr[mi] = &As[(wm * 64 + mi * 16 + lr) * 32 + ko];
#pragma unroll
  for (int ni = 0; ni < 4; ++ni) bptr[ni] = &Bs[(wnn * 64 + ni * 16 + lr) * 32 + ko];

  f32x4 acc[4][4];
#pragma unroll
  for (int mi = 0; mi < 4; ++mi)
#pragma unroll
    for (int ni = 0; ni < 4; ++ni) acc[mi][ni] = (f32x4){0.f, 0.f, 0.f, 0.f};

  for (int k0 = 0; k0 < HE; k0 += 32) {
    gld16(pA0, dA0); pA0 += 32;
    gld16(pA1, dA1); pA1 += 32;
    gld16(pB0, dB0); pB0 += 32;
    gld16(pB1, dB1); pB1 += 32;
    __syncthreads();
    bf16x8 af[4], bf[4];
#pragma unroll
    for (int mi = 0; mi < 4; ++mi) af[mi] = *(const bf16x8*)aptr[mi];
#pragma unroll
    for (int ni = 0; ni < 4; ++ni) bf[ni] = *(const bf16x8*)bptr[ni];
#pragma unroll
    for (int mi = 0; mi < 4; ++mi)
#pragma unroll
      for (int ni = 0; ni < 4; ++ni)
        acc[mi][ni] = __builtin_amdgcn_mfma_f32_16x16x32_bf16(af[mi], bf[ni], acc[mi][ni], 0, 0, 0);
    __syncthreads();
  }

#pragma unroll
  for (int ni = 0; ni < 4; ++ni) {
    int n = n0 + wnn * 64 + ni * 16 + lr;
    float bdv = bd[e * O_DIM + n];
#pragma unroll
    for (int mi = 0; mi < 4; ++mi) {
#pragma unroll
      for (int j = 0; j < 4; ++j) {
        int row = wm * 64 + mi * 16 + (lane >> 4) * 4 + j;
        int ts = rows_tok[row];
        if (ts < 0) continue;
        float sc = rows_sc[row];
        float v = sc * (acc[mi][ni][j] + bdv);
        if (PS) {
          out[(size_t)ts * O_DIM + n] = v;
        } else {
          int t = ts >> 1;
          atomicAdd(&out[(size_t)t * O_DIM + n], v);
        }
      }
    }
  }
}

__global__ __launch_bounds__(256) void gemm_down_fast(
    const short* __restrict__ H, const short* __restrict__ wdb, const float* __restrict__ bd,
    const int* __restrict__ counts, const int* __restrict__ tokslot,
    const float* __restrict__ scorelist, float* __restrict__ y) {
  int bid = blockIdx.x;          // grid = 4096
  int e = bid & 7;
  int rem = bid >> 3;
  down_core<0>(H, wdb, bd, counts, tokslot, scorelist, y, e, rem >> 4, rem & 15);
}

__global__ __launch_bounds__(256) void gemm_down_ps(
    const short* __restrict__ H, const short* __restrict__ wdb, const float* __restrict__ bd,
    const int* __restrict__ counts, const int* __restrict__ tokslot,
    const float* __restrict__ scorelist, float* __restrict__ part) {
  int bid = blockIdx.x;          // grid = 4096
  int e = bid & 7;
  int rem = bid >> 3;
  down_core<1>(H, wdb, bd, counts, tokslot, scorelist, part, e, rem >> 4, rem & 15);
}

// ================= FALLBACK PATH (fp32 weights, reg convert) ============
__global__ __launch_bounds__(256) void gemm_gu_slow(
    const short* __restrict__ xbf, const float* __restrict__ wg, const float* __restrict__ wu,
    const float* __restrict__ bg, const float* __restrict__ bu,
    const int* __restrict__ counts, const int* __restrict__ tokslot,
    short* __restrict__ H) {
  const int NT = 22, MT = 32;
  int bid = blockIdx.x;
  int e = bid / (MT * NT);
  int rem = bid % (MT * NT);
  int mt = rem / NT, nt = rem % NT;
  int R = counts[e];
  int m0 = mt * 128;
  if (m0 >= R) return;
  int n0 = nt * 64;

  __shared__ short As[128 * 40];
  __shared__ short Bs[2][64 * 40];
  __shared__ int rows_tok[128];

  int tid = threadIdx.x;
  if (tid < 128) {
    int pos = m0 + tid;
    rows_tok[tid] = (pos < R) ? tokslot[e * T_TOK + pos] : -1;
  }
  __syncthreads();

  int rA = tid >> 2, cA = tid & 3;
  int tsA0 = rows_tok[rA];
  int tsA1 = rows_tok[rA + 64];
  const short* srcA0 = xbf + (size_t)(tsA0 < 0 ? 0 : (tsA0 >> 1)) * D_DIM + cA * 8;
  const short* srcA1 = xbf + (size_t)(tsA1 < 0 ? 0 : (tsA1 >> 1)) * D_DIM + cA * 8;
  short* dstA0 = As + rA * 40 + cA * 8;
  short* dstA1 = As + (rA + 64) * 40 + cA * 8;

  const float* srcB[4];
  short* dstB[4];
#pragma unroll
  for (int j = 0; j < 4; ++j) {
    int idx = tid + j * 256;
    int mat = idx >> 9;
    int p = idx & 511;
    int row = p >> 3, c4 = p & 7;
    int sr = n0 + row;
    if (sr > HE - 1) sr = HE - 1;
    srcB[j] = (mat ? wu : wg) + ((size_t)e * HE + sr) * D_DIM + c4 * 4;
    dstB[j] = &Bs[mat][row * 40 + c4 * 4];
  }

  int lane = tid & 63, wid = tid >> 6;
  int wm = wid >> 1, wnn = wid & 1;
  int lr = lane & 15, lk = (lane >> 4) * 8;
  const short* aptr[4];
  const short* gptr[2];
  const short* uptr[2];
#pragma unroll
  for (int mi = 0; mi < 4; ++mi) aptr[mi] = As + (wm * 64 + mi * 16 + lr) * 40 + lk;
#pragma unroll
  for (int ni = 0; ni < 2; ++ni) {
    gptr[ni] = &Bs[0][(wnn * 32 + ni * 16 + lr) * 40 + lk];
    uptr[ni] = &Bs[1][(wnn * 32 + ni * 16 + lr) * 40 + lk];
  }

  f32x4 accg[4][2], accu[4][2];
#pragma unroll
  for (int mi = 0; mi < 4; ++mi)
#pragma unroll
    for (int ni = 0; ni < 2; ++ni) {
      accg[mi][ni] = (f32x4){0.f, 0.f, 0.f, 0.f};
      accu[mi][ni] = (f32x4){0.f, 0.f, 0.f, 0.f};
    }

  for (int k0 = 0; k0 < D_DIM; k0 += 32) {
    *(int4*)dstA0 = *(const int4*)(srcA0 + k0);
    *(int4*)dstA1 = *(const int4*)(srcA1 + k0);
#pragma unroll
    for (int j = 0; j < 4; ++j) {
      float4 v = *(const float4*)(srcB[j] + k0);
      *(unsigned long long*)dstB[j] = pack4bf(v.x, v.y, v.z, v.w);
    }
    __syncthreads();
    bf16x8 af[4], gf[2], uf[2];
#pragma unroll
    for (int mi = 0; mi < 4; ++mi) af[mi] = *(const bf16x8*)aptr[mi];
#pragma unroll
    for (int ni = 0; ni < 2; ++ni) {
      gf[ni] = *(const bf16x8*)gptr[ni];
      uf[ni] = *(const bf16x8*)uptr[ni];
    }
#pragma unroll
    for (int mi = 0; mi < 4; ++mi)
#pragma unroll
      for (int ni = 0; ni < 2; ++ni) {
        accg[mi][ni] = __builtin_amdgcn_mfma_f32_16x16x32_bf16(af[mi], gf[ni], accg[mi][ni], 0, 0, 0);
        accu[mi][ni] = __builtin_amdgcn_mfma_f32_16x16x32_bf16(af[mi], uf[ni], accu[mi][ni], 0, 0, 0);
      }
    __syncthreads();
  }

#pragma unroll
  for (int ni = 0; ni < 2; ++ni) {
    int n = n0 + wnn * 32 + ni * 16 + lr;
    if (n >= HE) continue;
    float bgv = bg[e * HE + n];
    float buv = bu[e * HE + n];
#pragma unroll
    for (int mi = 0; mi < 4; ++mi) {
#pragma unroll
      for (int j = 0; j < 4; ++j) {
        int row = wm * 64 + mi * 16 + (lane >> 4) * 4 + j;
        int ts = rows_tok[row];
        if (ts < 0) continue;
        float g = accg[mi][ni][j] + bgv;
        float u = accu[mi][ni][j] + buv;
        float h = (g / (1.f + expf(-g))) * u;
        H[(size_t)ts * HE + n] = f2bf(h);
      }
    }
  }
}

__global__ __launch_bounds__(256) void gemm_down_slow(
    const short* __restrict__ H, const float* __restrict__ wd, const float* __restrict__ bd,
    const int* __restrict__ counts, const int* __restrict__ tokslot,
    const float* __restrict__ scorelist, float* __restrict__ y) {
  const int NT = 32, MT = 32;
  int bid = blockIdx.x;
  int e = bid / (MT * NT);
  int rem = bid % (MT * NT);
  int mt = rem / NT, nt = rem % NT;
  int R = counts[e];
  int m0 = mt * 128;
  if (m0 >= R) return;
  int n0 = nt * 64;

  __shared__ short As[128 * 40];
  __shared__ short Bs[64 * 40];
  __shared__ int rows_tok[128];
  __shared__ float rows_sc[128];

  int tid = threadIdx.x;
  if (tid < 128) {
    int pos = m0 + tid;
    if (pos < R) {
      rows_tok[tid] = tokslot[e * T_TOK + pos];
      rows_sc[tid] = scorelist[e * T_TOK + pos];
    } else {
      rows_tok[tid] = -1;
      rows_sc[tid] = 0.f;
    }
  }
  __syncthreads();

  int rA = tid >> 2, cA = tid & 3;
  int tsA0 = rows_tok[rA];
  int tsA1 = rows_tok[rA + 64];
  const short* srcA0 = H + (size_t)(tsA0 < 0 ? 0 : tsA0) * HE + cA * 8;
  const short* srcA1 = H + (size_t)(tsA1 < 0 ? 0 : tsA1) * HE + cA * 8;
  short* dstA0 = As + rA * 40 + cA * 8;
  short* dstA1 = As + (rA + 64) * 40 + cA * 8;

  int rB = tid >> 3, cB = tid & 7;
  const float* srcB0 = wd + ((size_t)e * O_DIM + n0 + rB) * HE + cB * 4;
  const float* srcB1 = wd + ((size_t)e * O_DIM + n0 + rB + 32) * HE + cB * 4;
  short* dstB0 = Bs + rB * 40 + cB * 4;
  short* dstB1 = Bs + (rB + 32) * 40 + cB * 4;

  int lane = tid & 63, wid = tid >> 6;
  int wm = wid >> 1, wnn = wid & 1;
  int lr = lane & 15, lk = (lane >> 4) * 8;
  const short* aptr[4];
  const short* bptr[2];
#pragma unroll
  for (int mi = 0; mi < 4; ++mi) aptr[mi] = As + (wm * 64 + mi * 16 + lr) * 40 + lk;
#pragma unroll
  for (int ni = 0; ni < 2; ++ni) bptr[ni] = Bs + (wnn * 32 + ni * 16 + lr) * 40 + lk;

  f32x4 acc[4][2];
#pragma unroll
  for (int mi = 0; mi < 4; ++mi)
#pragma unroll
    for (int ni = 0; ni < 2; ++ni) acc[mi][ni] = (f32x4){0.f, 0.f, 0.f, 0.f};

  for (int k0 = 0; k0 < HE; k0 += 32) {
    *(int4*)dstA0 = *(const int4*)(srcA0 + k0);
    *(int4*)dstA1 = *(const int4*)(srcA1 + k0);
    {
      float4 v0 = *(const float4*)(srcB0 + k0);
      float4 v1 = *(const float4*)(srcB1 + k0);
      *(unsigned long long*)dstB0 = pack4bf(v0.x, v0.y, v0.z, v0.w);
      *(unsigned long long*)dstB1 = pack4bf(v1.x, v1.y, v1.z, v1.w);
    }
    __syncthreads();
    bf16x8 af[4], bf[2];
#pragma unroll
    for (int mi = 0; mi < 4; ++mi) af[mi] = *(const bf16x8*)aptr[mi];
#pragma unroll
    for (int ni = 0; ni < 2; ++ni) bf[ni] = *(const bf16x8*)bptr[ni];
#pragma unroll
    for (int mi = 0; mi < 4; ++mi)
#pragma unroll
      for (int ni = 0; ni < 2; ++ni)
        acc[mi][ni] = __builtin_amdgcn_mfma_f32_16x16x32_bf16(af[mi], bf[ni], acc[mi][ni], 0, 0, 0);
    __syncthreads();
  }

#pragma unroll
  for (int ni = 0; ni < 2; ++ni) {
    int n = n0 + wnn * 32 + ni * 16 + lr;
    float bdv = bd[e * O_DIM + n];
#pragma unroll
    for (int mi = 0; mi < 4; ++mi) {
#pragma unroll
      for (int j = 0; j < 4; ++j) {
        int row = wm * 64 + mi * 16 + (lane >> 4) * 4 + j;
        int ts = rows_tok[row];
        if (ts < 0) continue;
        float sc = rows_sc[row];
        int t = ts >> 1;
        atomicAdd(&y[(size_t)t * O_DIM + n], sc * (acc[mi][ni][j] + bdv));
      }
    }
  }
}

extern "C" void kernel_launch(void* const* d_in, const int* in_sizes, int n_in,
                              void* d_out, int out_size, void* d_ws, size_t ws_size,
                              hipStream_t stream) {
  const float* x     = (const float*)d_in[0];
  const float* noise = (const float*)d_in[1];
  const float* wg1   = (const float*)d_in[2];
  const float* wg2   = (const float*)d_in[3];
  const float* wn    = (const float*)d_in[4];
  const float* wg    = (const float*)d_in[5];
  const float* wu    = (const float*)d_in[6];
  const float* wd    = (const float*)d_in[7];
  const float* bg    = (const float*)d_in[8];
  const float* bu    = (const float*)d_in[9];
  const float* bd    = (const float*)d_in[10];
  float* y = (float*)d_out;

  // layout: ctl | tokslot@256 | scorelst@131328 | xbf@262400 | H@17039616
  //   wgb@39584000 | wub@84672768 -> 129761536 (TIER1)
  //   wdb2@129761536 -> 174850304 (TIER2)
  //   part@174850304 (67108864) -> 241959168 (TIER3)
  char* ws = (char*)d_ws;
  float* imp      = (float*)(ws + 0);
  float* loadv    = (float*)(ws + 32);
  int*   counts   = (int*)(ws + 64);
  int*   tokslot  = (int*)(ws + 256);
  float* scorelst = (float*)(ws + 131328);
  short* xbf      = (short*)(ws + 262400);
  short* Hbuf     = (short*)(ws + 17039616);
  short* wgb      = (short*)(ws + 39584000);
  short* wub      = (short*)(ws + 84672768);
  short* wdb1     = (short*)(ws + 39584000);    // tier1: reuse wgb after gemm_gu
  short* wdb2     = (short*)(ws + 129761536);   // tier2+: independent
  float* part     = (float*)(ws + 174850304);   // tier3: per-slot partials
  const size_t TIER1 = 129761536;
  const size_t TIER2 = 174850304;
  const size_t TIER3 = 241959168;

  hipMemsetAsync(d_ws, 0, 96, stream);

  if (ws_size >= TIER3) {
    prep_mega<<<6656, 256, 0, stream>>>(x, noise, wg1, wg2, wn, wg, wu, wd, wgb, wub, wdb2,
                                        imp, loadv, counts, tokslot, scorelst, xbf);
    loss_kernel<<<1, 64, 0, stream>>>(imp, loadv, y + (size_t)T_TOK * O_DIM);
    gemm_gu_fast<<<5632, 256, 0, stream>>>(xbf, wgb, wub, bg, bu, counts, tokslot, Hbuf);
    gemm_down_ps<<<4096, 256, 0, stream>>>(Hbuf, wdb2, bd, counts, tokslot, scorelst, part);
    combine_y<<<2048, 256, 0, stream>>>(part, y);
  } else if (ws_size >= TIER2) {
    hipMemsetAsync(d_out, 0, (size_t)T_TOK * O_DIM * sizeof(float), stream);
    prep_mega<<<6656, 256, 0, stream>>>(x, noise, wg1, wg2, wn, wg, wu, wd, wgb, wub, wdb2,
                                        imp, loadv, counts, tokslot, scorelst, xbf);
    loss_kernel<<<1, 64, 0, stream>>>(imp, loadv, y + (size_t)T_TOK * O_DIM);
    gemm_gu_fast<<<5632, 256, 0, stream>>>(xbf, wgb, wub, bg, bu, counts, tokslot, Hbuf);
    gemm_down_fast<<<4096, 256, 0, stream>>>(Hbuf, wdb2, bd, counts, tokslot, scorelst, y);
  } else if (ws_size >= TIER1) {
    hipMemsetAsync(d_out, 0, (size_t)T_TOK * O_DIM * sizeof(float), stream);
    prep_mega<<<4608, 256, 0, stream>>>(x, noise, wg1, wg2, wn, wg, wu, wd, wgb, wub, wdb2,
                                        imp, loadv, counts, tokslot, scorelst, xbf);
    loss_kernel<<<1, 64, 0, stream>>>(imp, loadv, y + (size_t)T_TOK * O_DIM);
    gemm_gu_fast<<<5632, 256, 0, stream>>>(xbf, wgb, wub, bg, bu, counts, tokslot, Hbuf);
    cvt_seg<<<2048, 256, 0, stream>>>(wd, wdb1);
    gemm_down_fast<<<4096, 256, 0, stream>>>(Hbuf, wdb1, bd, counts, tokslot, scorelst, y);
  } else {
    hipMemsetAsync(d_out, 0, (size_t)T_TOK * O_DIM * sizeof(float), stream);
    prep_mega<<<512, 256, 0, stream>>>(x, noise, wg1, wg2, wn, wg, wu, wd, wgb, wub, wdb2,
                                       imp, loadv, counts, tokslot, scorelst, xbf);
    loss_kernel<<<1, 64, 0, stream>>>(imp, loadv, y + (size_t)T_TOK * O_DIM);
    gemm_gu_slow<<<E_EXP * 32 * 22, 256, 0, stream>>>(xbf, wg, wu, bg, bu, counts, tokslot, Hbuf);
    gemm_down_slow<<<E_EXP * 32 * 32, 256, 0, stream>>>(Hbuf, wd, bd, counts, tokslot, scorelst, y);
  }
}